// Round 1
// baseline (783.236 us; speedup 1.0000x reference)
//
#include <hip/hip_runtime.h>
#include <math.h>

// Problem constants
//   x: [1,32,32,32,80]  (80 = 32 scalars + 16 vectors*3)
//   conv out: 96 = 48 (32 scalars + 16 gates) + 16 vectors*3
//   kernel low-rank basis: 12 = 3 radial * {1, Yx, Yy, Yz}
//   output: [1,64,64,64,80] fp32

__device__ __forceinline__ int eps3(int a, int m, int b) {
    if (a == b || a == m || m == b) return 0;
    return ((a==0&&m==1&&b==2)||(a==1&&m==2&&b==0)||(a==2&&m==0&&b==1)) ? 1 : -1;
}

// ---------------------------------------------------------------- B table
// B[tap][j], tap = (kd*5+kh)*5+kw, j = r*4+alpha; alpha 0 -> 1, 1..3 -> Y_{d,h,w}
__global__ void build_B(float* __restrict__ B) {
    int idx = threadIdx.x + blockIdx.x * 256;
    if (idx >= 125 * 12) return;
    int tap = idx / 12, j = idx % 12;
    int r = j >> 2, al = j & 3;
    int kd = tap / 25, kh = (tap / 5) % 5, kw = tap % 5;
    float cd = (float)(kd - 2), ch = (float)(kh - 2), cw = (float)(kw - 2);
    float n2 = cd*cd + ch*ch + cw*cw;
    float val = 0.f;
    if (n2 <= 6.25f) {                       // mask: |r| <= 2.5
        float norm = sqrtf(n2);
        float tt = (norm - 1.25f * (float)r) * 0.8f;   // /1.25
        float R = expf(-tt * tt);
        if (al == 0) val = R;
        else if (n2 > 0.f) {
            float c = (al == 1) ? cd : (al == 2 ? ch : cw);
            val = R * 1.7320508075688772f * c / norm;  // sqrt(3)*c/|r|
        }
    }
    B[idx] = val;
}

// ---------------------------------------------------------------- W matrices
// W[conv][j*80+ci][co], j = r*4+alpha.  2*12*80*96 = 184320 entries.
__global__ void build_W(float* __restrict__ W,
    const float* __restrict__ ss1, const float* __restrict__ sv1,
    const float* __restrict__ vs1, const float* __restrict__ vv01, const float* __restrict__ vv11,
    const float* __restrict__ ss2, const float* __restrict__ sv2,
    const float* __restrict__ vs2, const float* __restrict__ vv02, const float* __restrict__ vv12)
{
    int idx = threadIdx.x + blockIdx.x * 256;
    if (idx >= 184320) return;
    int conv = idx / 92160;
    int rem  = idx % 92160;
    int j  = rem / 7680;
    int ci = (rem / 96) % 80;
    int co = rem % 96;
    int r = j >> 2, al = j & 3;
    const float* ss  = conv ? ss2  : ss1;
    const float* sv  = conv ? sv2  : sv1;
    const float* vs  = conv ? vs2  : vs1;
    const float* vv0 = conv ? vv02 : vv01;
    const float* vv1 = conv ? vv12 : vv11;
    float val = 0.f;
    if (ci < 32) {
        if (co < 48) { if (al == 0) val = ss[(r*32 + ci)*48 + co]; }
        else {
            int o = (co - 48) / 3, m = (co - 48) % 3;
            if (al == m + 1) val = sv[(r*32 + ci)*16 + o];
        }
    } else {
        int i = (ci - 32) / 3, a = (ci - 32) % 3;
        if (co < 48) { if (al == a + 1) val = vs[(r*16 + i)*48 + co] * 0.5773502691896258f; }
        else {
            int o = (co - 48) / 3, b = (co - 48) % 3;
            if (al == 0) { if (a == b) val = vv0[(r*16 + i)*16 + o]; }
            else {
                int e = eps3(a, al - 1, b);
                if (e) val = vv1[(r*16 + i)*16 + o] * (float)e * 0.7071067811865476f;
            }
        }
    }
    W[idx] = val;
}

// ---------------------------------------------------------------- Stage A
// z[vl][j*80+ci] = sum_tap B[tap][j] * x[v+tap][ci]    (zero-padded SAME)
__global__ __launch_bounds__(256) void basis_conv(
    const float* __restrict__ xin, float* __restrict__ z,
    const float* __restrict__ B, int d0)
{
    int t = threadIdx.x + blockIdx.x * 256;
    int ci = t % 80;
    int vl = t / 80;                    // slab-local voxel
    int v  = d0 * 1024 + vl;
    int d = v >> 10, h = (v >> 5) & 31, w = v & 31;
    float acc[12];
    #pragma unroll
    for (int j = 0; j < 12; j++) acc[j] = 0.f;
    for (int kd = 0; kd < 5; kd++) {
        int dd = d + kd - 2;
        if (dd < 0 || dd >= 32) continue;
        for (int kh = 0; kh < 5; kh++) {
            int hh = h + kh - 2;
            if (hh < 0 || hh >= 32) continue;
            const float* xrow = xin + (((dd << 5) + hh) << 5) * 80 + ci;
            int tapb = (kd * 5 + kh) * 5;
            int dx = kd - 2, dy = kh - 2;
            int n2dh = dx*dx + dy*dy;
            #pragma unroll
            for (int kw = 0; kw < 5; kw++) {
                int dz = kw - 2;
                if (n2dh + dz*dz > 6) continue;     // masked tap (B==0)
                int ww = w + kw - 2;
                if (ww < 0 || ww >= 32) continue;
                float xv = xrow[ww * 80];
                const float* Bp = B + (tapb + kw) * 12;
                #pragma unroll
                for (int j = 0; j < 12; j++) acc[j] += Bp[j] * xv;
            }
        }
    }
    float* zp = z + (size_t)vl * 960 + ci;
    #pragma unroll
    for (int j = 0; j < 12; j++) zp[j * 80] = acc[j];
}

// ---------------------------------------------------------------- Stage B
// y[v][0:96] = z[v][0:960] @ W[960][96]; gate; write 80 channels.
// Block: 256 thr, tile 128 voxels x 96 co, per-thread 8v x 6co.
__global__ __launch_bounds__(256) void gemm_gate(
    const float* __restrict__ z, const float* __restrict__ W,
    float* __restrict__ xout, int d0)
{
    __shared__ float smem[128 * 65 + 64 * 96];
    float* zt = smem;               // [128][65]  (+1 pad: odd stride, conflict-free)
    float* wt = smem + 128 * 65;    // [64][96]
    int t = threadIdx.x;
    int vg = t >> 4, cg = t & 15;
    int v0 = vg * 8, co0 = cg * 6;
    int vbase = blockIdx.x * 128;   // slab-local
    float acc[8][6];
    #pragma unroll
    for (int i = 0; i < 8; i++)
        #pragma unroll
        for (int j = 0; j < 6; j++) acc[i][j] = 0.f;

    for (int kc = 0; kc < 15; kc++) {
        #pragma unroll
        for (int l = 0; l < 8; l++) {            // z tile 128x64
            int idx = t + l * 256;
            int row = idx >> 4, c4 = idx & 15;
            float4 zv4 = *reinterpret_cast<const float4*>(
                z + (size_t)(vbase + row) * 960 + kc * 64 + c4 * 4);
            float* dst = zt + row * 65 + c4 * 4;
            dst[0] = zv4.x; dst[1] = zv4.y; dst[2] = zv4.z; dst[3] = zv4.w;
        }
        #pragma unroll
        for (int l = 0; l < 6; l++) {            // W tile 64x96
            int idx = t + l * 256;
            int row = idx / 24, c4 = idx % 24;
            *reinterpret_cast<float4*>(wt + row * 96 + c4 * 4) =
                *reinterpret_cast<const float4*>(W + (size_t)(kc * 64 + row) * 96 + c4 * 4);
        }
        __syncthreads();
        #pragma unroll 2
        for (int kk = 0; kk < 64; kk++) {
            float zv[8], wv[6];
            #pragma unroll
            for (int i = 0; i < 8; i++) zv[i] = zt[(v0 + i) * 65 + kk];
            #pragma unroll
            for (int j = 0; j < 6; j++) wv[j] = wt[kk * 96 + co0 + j];
            #pragma unroll
            for (int i = 0; i < 8; i++)
                #pragma unroll
                for (int j = 0; j < 6; j++) acc[i][j] += zv[i] * wv[j];
        }
        __syncthreads();
    }
    // y tile -> smem (overlay; all tile reads done past the barrier)
    float* y = smem;                 // [128][96]
    #pragma unroll
    for (int i = 0; i < 8; i++)
        #pragma unroll
        for (int j = 0; j < 6; j++) y[(v0 + i) * 96 + co0 + j] = acc[i][j];
    __syncthreads();
    // gate: s=relu(y[0:32]); g=sigmoid(y[32:48]); v=y[48:96]*g[i]
    int gbase = d0 * 1024 + vbase;
    for (int idx = t; idx < 128 * 80; idx += 256) {
        int vr = idx / 80, c = idx % 80;
        const float* yr = y + vr * 96;
        float val;
        if (c < 32) val = fmaxf(yr[c], 0.f);
        else {
            int q = c - 32;
            float g = 1.f / (1.f + __expf(-yr[32 + q / 3]));
            val = yr[48 + q] * g;
        }
        xout[(size_t)(gbase + vr) * 80 + c] = val;
    }
}

// ---------------------------------------------------------------- Final head
// out[f][80]: upsample x2, p = w_pos*(ceil(f/2)-16), tensor products + linears.
__global__ __launch_bounds__(256) void final_k(
    const float* __restrict__ x2, const float* __restrict__ wls,
    const float* __restrict__ wlv, const float* __restrict__ wpos,
    float* __restrict__ out)
{
    __shared__ float lt[16 * 161];   // per voxel: [0:16) t_s, [16:160) tv[c*3+m]
    __shared__ float s_wls[512];     // [16][32]
    __shared__ float s_wlv[768];     // [48][16]
    int t = threadIdx.x;
    for (int i = t; i < 512; i += 256) s_wls[i] = wls[i];
    for (int i = t; i < 768; i += 256) s_wlv[i] = wlv[i];
    float wp = wpos[0];
    int F0 = blockIdx.x * 16;
    int fd = F0 >> 12, fh = (F0 >> 6) & 63, fw0 = F0 & 63;
    {   // phase 1: build t_s / tv per voxel
        int vi = t >> 4, sub = t & 15;
        int fw = fw0 + vi;
        const float* xp = x2 + (size_t)((((fd >> 1) << 5) + (fh >> 1)) * 32 + (fw >> 1)) * 80;
        float p0 = wp * (float)(((fd + 1) >> 1) - 16);
        float p1 = wp * (float)(((fh + 1) >> 1) - 16);
        float p2 = wp * (float)(((fw + 1) >> 1) - 16);
        float pm[3] = {p0, p1, p2};
        #pragma unroll
        for (int l = 0; l < 10; l++) {
            int q = sub * 10 + l;
            float val;
            if (q < 16) {            // t_s[c] = V[c].p / sqrt(3)
                float vx = xp[32 + q*3], vy = xp[32 + q*3 + 1], vz = xp[32 + q*3 + 2];
                val = (vx * p0 + vy * p1 + vz * p2) * 0.5773502691896258f;
            } else {
                int q2 = q - 16, c = q2 / 3, m = q2 % 3;
                if (c < 32) val = xp[c] * pm[m];              // S[c]*p[m]
                else {                                        // (VxP)[m]/sqrt2
                    int cv = c - 32;
                    float vx = xp[32 + cv*3], vy = xp[32 + cv*3 + 1], vz = xp[32 + cv*3 + 2];
                    float cr = (m == 0) ? (vy * p2 - vz * p1)
                             : (m == 1) ? (vz * p0 - vx * p2)
                                        : (vx * p1 - vy * p0);
                    val = cr * 0.7071067811865476f;
                }
            }
            lt[vi * 161 + q] = val;
        }
    }
    __syncthreads();
    // phase 2: output linears
    int vi = t >> 4, cg = t & 15;
    int fw = fw0 + vi;
    size_t obase = (size_t)(((fd * 64) + fh) * 64 + fw) * 80;
    const float* L = lt + vi * 161;
    #pragma unroll
    for (int l = 0; l < 5; l++) {
        int c = cg * 5 + l;
        float sum = 0.f;
        if (c < 32) {
            #pragma unroll
            for (int k = 0; k < 16; k++) sum += L[k] * s_wls[k * 32 + c];
            sum *= 0.25f;                         // /sqrt(16)
        } else {
            int q = c - 32, o = q / 3, m = q % 3;
            #pragma unroll
            for (int k = 0; k < 48; k++) sum += L[16 + k * 3 + m] * s_wlv[k * 16 + o];
            sum *= 0.14433756729740643f;          // /sqrt(48)
        }
        out[obase + c] = sum;
    }
}

// ----------------------------------------------------------------
extern "C" void kernel_launch(void* const* d_in, const int* in_sizes, int n_in,
                              void* d_out, int out_size, void* d_ws, size_t ws_size,
                              hipStream_t stream)
{
    const float* x    = (const float*)d_in[0];
    const float* wpos = (const float*)d_in[11];
    const float* wls  = (const float*)d_in[12];
    const float* wlv  = (const float*)d_in[13];
    float* out = (float*)d_out;
    float* ws  = (float*)d_ws;

    float* B  = ws;                         // 1500 -> pad 1536
    float* W  = ws + 1536;                  // 184320
    float* x1 = ws + 1536 + 184320;         // 32768*80
    float* x2 = x1 + 2621440;
    float* z  = x2 + 2621440;
    size_t fixedf = 1536 + 184320 + 2ull * 2621440;
    size_t wsf = ws_size / 4;
    int slabD = 32;                          // shrink z slab if ws is small
    while (slabD > 1 && fixedf + (size_t)1024 * slabD * 960 > wsf) slabD >>= 1;

    build_B<<<6, 256, 0, stream>>>(B);
    build_W<<<720, 256, 0, stream>>>(W,
        (const float*)d_in[1], (const float*)d_in[2], (const float*)d_in[3],
        (const float*)d_in[4], (const float*)d_in[5],
        (const float*)d_in[6], (const float*)d_in[7], (const float*)d_in[8],
        (const float*)d_in[9], (const float*)d_in[10]);

    for (int d0 = 0; d0 < 32; d0 += slabD) {
        basis_conv<<<slabD * 320, 256, 0, stream>>>(x, z, B, d0);
        gemm_gate<<<slabD * 8, 256, 0, stream>>>(z, W, x1, d0);
    }
    for (int d0 = 0; d0 < 32; d0 += slabD) {
        basis_conv<<<slabD * 320, 256, 0, stream>>>(x1, z, B, d0);
        gemm_gate<<<slabD * 8, 256, 0, stream>>>(z, W + 92160, x2, d0);
    }
    final_k<<<16384, 256, 0, stream>>>(x2, wls, wlv, wpos, out);
}

// Round 2
// 611.256 us; speedup vs baseline: 1.2814x; 1.2814x over previous
//
#include <hip/hip_runtime.h>
#include <math.h>

// Problem constants
//   x: [1,32,32,32,80]  (80 = 32 scalars + 16 vectors*3)
//   conv out: 96 = 48 (32 scalars + 16 gates) + 16 vectors*3
//   kernel low-rank basis: 12 = 3 radial * {1, Yx, Yy, Yz}
//   output: [1,64,64,64,80] fp32

__device__ __forceinline__ int eps3(int a, int m, int b) {
    if (a == b || a == m || m == b) return 0;
    return ((a==0&&m==1&&b==2)||(a==1&&m==2&&b==0)||(a==2&&m==0&&b==1)) ? 1 : -1;
}

// ---------------------------------------------------------------- B table
// B[tap][j], tap = (kd*5+kh)*5+kw, j = r*4+alpha; alpha 0 -> 1, 1..3 -> Y_{d,h,w}
__global__ void build_B(float* __restrict__ B) {
    int idx = threadIdx.x + blockIdx.x * 256;
    if (idx >= 125 * 12) return;
    int tap = idx / 12, j = idx % 12;
    int r = j >> 2, al = j & 3;
    int kd = tap / 25, kh = (tap / 5) % 5, kw = tap % 5;
    float cd = (float)(kd - 2), ch = (float)(kh - 2), cw = (float)(kw - 2);
    float n2 = cd*cd + ch*ch + cw*cw;
    float val = 0.f;
    if (n2 <= 6.25f) {                       // mask: |r| <= 2.5
        float norm = sqrtf(n2);
        float tt = (norm - 1.25f * (float)r) * 0.8f;   // /1.25
        float R = expf(-tt * tt);
        if (al == 0) val = R;
        else if (n2 > 0.f) {
            float c = (al == 1) ? cd : (al == 2 ? ch : cw);
            val = R * 1.7320508075688772f * c / norm;  // sqrt(3)*c/|r|
        }
    }
    B[idx] = val;
}

// ---------------------------------------------------------------- W matrices
// W[conv][j*80+ci][co], j = r*4+alpha.  2*12*80*96 = 184320 entries.
__global__ void build_W(float* __restrict__ W,
    const float* __restrict__ ss1, const float* __restrict__ sv1,
    const float* __restrict__ vs1, const float* __restrict__ vv01, const float* __restrict__ vv11,
    const float* __restrict__ ss2, const float* __restrict__ sv2,
    const float* __restrict__ vs2, const float* __restrict__ vv02, const float* __restrict__ vv12)
{
    int idx = threadIdx.x + blockIdx.x * 256;
    if (idx >= 184320) return;
    int conv = idx / 92160;
    int rem  = idx % 92160;
    int j  = rem / 7680;
    int ci = (rem / 96) % 80;
    int co = rem % 96;
    int r = j >> 2, al = j & 3;
    const float* ss  = conv ? ss2  : ss1;
    const float* sv  = conv ? sv2  : sv1;
    const float* vs  = conv ? vs2  : vs1;
    const float* vv0 = conv ? vv02 : vv01;
    const float* vv1 = conv ? vv12 : vv11;
    float val = 0.f;
    if (ci < 32) {
        if (co < 48) { if (al == 0) val = ss[(r*32 + ci)*48 + co]; }
        else {
            int o = (co - 48) / 3, m = (co - 48) % 3;
            if (al == m + 1) val = sv[(r*32 + ci)*16 + o];
        }
    } else {
        int i = (ci - 32) / 3, a = (ci - 32) % 3;
        if (co < 48) { if (al == a + 1) val = vs[(r*16 + i)*48 + co] * 0.5773502691896258f; }
        else {
            int o = (co - 48) / 3, b = (co - 48) % 3;
            if (al == 0) { if (a == b) val = vv0[(r*16 + i)*16 + o]; }
            else {
                int e = eps3(a, al - 1, b);
                if (e) val = vv1[(r*16 + i)*16 + o] * (float)e * 0.7071067811865476f;
            }
        }
    }
    W[idx] = val;
}

// ---------------------------------------------------------------- Stage A
// z[vl][j*80+ci] = sum_tap B[tap][j] * x[v+tap][ci]    (zero-padded SAME)
__global__ __launch_bounds__(256) void basis_conv(
    const float* __restrict__ xin, float* __restrict__ z,
    const float* __restrict__ B, int d0)
{
    int t = threadIdx.x + blockIdx.x * 256;
    int ci = t % 80;
    int vl = t / 80;                    // slab-local voxel
    int v  = d0 * 1024 + vl;
    int d = v >> 10, h = (v >> 5) & 31, w = v & 31;
    float acc[12];
    #pragma unroll
    for (int j = 0; j < 12; j++) acc[j] = 0.f;
    for (int kd = 0; kd < 5; kd++) {
        int dd = d + kd - 2;
        if (dd < 0 || dd >= 32) continue;
        for (int kh = 0; kh < 5; kh++) {
            int hh = h + kh - 2;
            if (hh < 0 || hh >= 32) continue;
            const float* xrow = xin + (((dd << 5) + hh) << 5) * 80 + ci;
            int tapb = (kd * 5 + kh) * 5;
            int dx = kd - 2, dy = kh - 2;
            int n2dh = dx*dx + dy*dy;
            #pragma unroll
            for (int kw = 0; kw < 5; kw++) {
                int dz = kw - 2;
                if (n2dh + dz*dz > 6) continue;     // masked tap (B==0)
                int ww = w + kw - 2;
                if (ww < 0 || ww >= 32) continue;
                float xv = xrow[ww * 80];
                const float* Bp = B + (tapb + kw) * 12;
                #pragma unroll
                for (int j = 0; j < 12; j++) acc[j] += Bp[j] * xv;
            }
        }
    }
    float* zp = z + (size_t)vl * 960 + ci;
    #pragma unroll
    for (int j = 0; j < 12; j++) zp[j * 80] = acc[j];
}

// ---------------------------------------------------------------- Stage B
// y[v][0:96] = z[v][0:960] @ W[960][96]; gate; write 80 channels.
// Block: 256 thr, tile 128 voxels x 96 co, per-thread 8v x 6co.
__global__ __launch_bounds__(256) void gemm_gate(
    const float* __restrict__ z, const float* __restrict__ W,
    float* __restrict__ xout, int d0)
{
    __shared__ float smem[128 * 65 + 64 * 96];
    float* zt = smem;               // [128][65]  (+1 pad: odd stride, conflict-free)
    float* wt = smem + 128 * 65;    // [64][96]
    int t = threadIdx.x;
    int vg = t >> 4, cg = t & 15;
    int v0 = vg * 8, co0 = cg * 6;
    int vbase = blockIdx.x * 128;   // slab-local
    float acc[8][6];
    #pragma unroll
    for (int i = 0; i < 8; i++)
        #pragma unroll
        for (int j = 0; j < 6; j++) acc[i][j] = 0.f;

    for (int kc = 0; kc < 15; kc++) {
        #pragma unroll
        for (int l = 0; l < 8; l++) {            // z tile 128x64
            int idx = t + l * 256;
            int row = idx >> 4, c4 = idx & 15;
            float4 zv4 = *reinterpret_cast<const float4*>(
                z + (size_t)(vbase + row) * 960 + kc * 64 + c4 * 4);
            float* dst = zt + row * 65 + c4 * 4;
            dst[0] = zv4.x; dst[1] = zv4.y; dst[2] = zv4.z; dst[3] = zv4.w;
        }
        #pragma unroll
        for (int l = 0; l < 6; l++) {            // W tile 64x96
            int idx = t + l * 256;
            int row = idx / 24, c4 = idx % 24;
            *reinterpret_cast<float4*>(wt + row * 96 + c4 * 4) =
                *reinterpret_cast<const float4*>(W + (size_t)(kc * 64 + row) * 96 + c4 * 4);
        }
        __syncthreads();
        #pragma unroll 2
        for (int kk = 0; kk < 64; kk++) {
            float zv[8], wv[6];
            #pragma unroll
            for (int i = 0; i < 8; i++) zv[i] = zt[(v0 + i) * 65 + kk];
            #pragma unroll
            for (int j = 0; j < 6; j++) wv[j] = wt[kk * 96 + co0 + j];
            #pragma unroll
            for (int i = 0; i < 8; i++)
                #pragma unroll
                for (int j = 0; j < 6; j++) acc[i][j] += zv[i] * wv[j];
        }
        __syncthreads();
    }
    // y tile -> smem (overlay; all tile reads done past the barrier)
    float* y = smem;                 // [128][96]
    #pragma unroll
    for (int i = 0; i < 8; i++)
        #pragma unroll
        for (int j = 0; j < 6; j++) y[(v0 + i) * 96 + co0 + j] = acc[i][j];
    __syncthreads();
    // gate: s=relu(y[0:32]); g=sigmoid(y[32:48]); v=y[48:96]*g[i]
    int gbase = d0 * 1024 + vbase;
    for (int idx = t; idx < 128 * 80; idx += 256) {
        int vr = idx / 80, c = idx % 80;
        const float* yr = y + vr * 96;
        float val;
        if (c < 32) val = fmaxf(yr[c], 0.f);
        else {
            int q = c - 32;
            float g = 1.f / (1.f + __expf(-yr[32 + q / 3]));
            val = yr[48 + q] * g;
        }
        xout[(size_t)(gbase + vr) * 80 + c] = val;
    }
}

// ---------------------------------------------------------------- Final head (v2)
// Low-rank precompose per COARSE voxel:
//   M[o,m]  = sum_{c<16} V[c,m] * wl_s[c,o]          (o<32)
//   A[o]    = sum_{c<32} S[c]   * wl_v[c,o]          (o<16)
//   W2[o,m] = sum_{c<16} V[c,m] * wl_v[32+c,o]       (o<16)
// Then per fine voxel (p varies only in sign/offset over the 8 children):
//   S_out[o]   = (M[o,:].p) * s
//   V_out[o,m] = (A[o]*p[m] + (W2[o,:] x p)[m]/sqrt2) * s
// with s = 1/(sqrt3*4) = 1/sqrt(48) = 0.14433757 for both.
// Block: 256 thr = 16 coarse voxels along w (one (cd,ch) row-half).
__global__ __launch_bounds__(256) void final_k(
    const float* __restrict__ x2, const float* __restrict__ wls,
    const float* __restrict__ wlv, const float* __restrict__ wpos,
    float* __restrict__ out)
{
    __shared__ float xv[16 * 81];     // per-voxel input, pad 81 (bank offset 17/voxel)
    __shared__ float coeff[16 * 161]; // [M:96][A:16][W2:48], pad 161 (bank offset 1/voxel)
    __shared__ float s_wls[512];      // [16][32]
    __shared__ float s_wlv[768];      // [48][16]
    int t = threadIdx.x;
    int bid = blockIdx.x;
    int cw0 = (bid & 1) * 16;
    int ch  = (bid >> 1) & 31;
    int cd  = bid >> 6;
    float wp = wpos[0];

    // phase 0: cooperative loads
    {
        int base = ((cd * 32 + ch) * 32 + cw0) * 80;
        #pragma unroll
        for (int i = t; i < 1280; i += 256) {
            int vi = i / 80, c = i % 80;
            xv[vi * 81 + c] = x2[base + i];
        }
        for (int i = t; i < 512; i += 256) s_wls[i] = wls[i];
        for (int i = t; i < 768; i += 256) s_wlv[i] = wlv[i];
    }
    __syncthreads();

    // phase 1: per-coarse-voxel coefficients (160 outputs, 16 thr/voxel, 10 each)
    {
        int vi = t >> 4, j = t & 15;
        const float* xp = xv + vi * 81;
        float* cf = coeff + vi * 161;
        #pragma unroll
        for (int l = 0; l < 10; l++) {
            int q = l * 16 + j;           // branch is uniform per l
            float sum = 0.f;
            if (q < 96) {                 // M[o,m]
                int o = q / 3, m = q % 3;
                #pragma unroll
                for (int c = 0; c < 16; c++) sum += xp[32 + c * 3 + m] * s_wls[c * 32 + o];
            } else if (q < 112) {         // A[o]
                int o = q - 96;
                #pragma unroll
                for (int c = 0; c < 32; c++) sum += xp[c] * s_wlv[c * 16 + o];
            } else {                      // W2[o,m]
                int q2 = q - 112; int o = q2 / 3, m = q2 % 3;
                #pragma unroll
                for (int c = 0; c < 16; c++) sum += xp[32 + c * 3 + m] * s_wlv[(32 + c) * 16 + o];
            }
            cf[q] = sum;
        }
    }
    __syncthreads();

    // phase 2: 4 (fd,fh) children x 2560 coalesced outputs
    const float scale = 0.14433756729740643f;   // 1/sqrt(48) == 1/(sqrt3*4)
    #pragma unroll
    for (int f01 = 0; f01 < 4; f01++) {
        int fd = 2 * cd + (f01 >> 1), fh = 2 * ch + (f01 & 1);
        float p0 = wp * (float)(cd + (f01 >> 1) - 16);
        float p1 = wp * (float)(ch + (f01 & 1) - 16);
        size_t obase = (size_t)((fd * 64 + fh) * 64 + cw0 * 2) * 80;
        #pragma unroll
        for (int it = 0; it < 10; it++) {
            int idx = it * 256 + t;
            int fwl = idx / 80, c = idx - fwl * 80;
            int vi = fwl >> 1;
            float p2 = wp * (float)(cw0 + vi + (fwl & 1) - 16);
            const float* cf = coeff + vi * 161;
            float val;
            if (c < 32) {
                val = cf[c * 3] * p0 + cf[c * 3 + 1] * p1 + cf[c * 3 + 2] * p2;
            } else {
                int q = c - 32, o = q / 3, m = q - o * 3;
                float A = cf[96 + o];
                const float* w2 = cf + 112 + o * 3;
                float pm, crm;
                if (m == 0)      { pm = p0; crm = w2[1] * p2 - w2[2] * p1; }
                else if (m == 1) { pm = p1; crm = w2[2] * p0 - w2[0] * p2; }
                else             { pm = p2; crm = w2[0] * p1 - w2[1] * p0; }
                val = A * pm + crm * 0.7071067811865476f;
            }
            out[obase + idx] = val * scale;
        }
    }
}

// ----------------------------------------------------------------
extern "C" void kernel_launch(void* const* d_in, const int* in_sizes, int n_in,
                              void* d_out, int out_size, void* d_ws, size_t ws_size,
                              hipStream_t stream)
{
    const float* x    = (const float*)d_in[0];
    const float* wpos = (const float*)d_in[11];
    const float* wls  = (const float*)d_in[12];
    const float* wlv  = (const float*)d_in[13];
    float* out = (float*)d_out;
    float* ws  = (float*)d_ws;

    float* B  = ws;                         // 1500 -> pad 1536
    float* W  = ws + 1536;                  // 184320
    float* x1 = ws + 1536 + 184320;         // 32768*80
    float* x2 = x1 + 2621440;
    float* z  = x2 + 2621440;
    size_t fixedf = 1536 + 184320 + 2ull * 2621440;
    size_t wsf = ws_size / 4;
    int slabD = 32;                          // shrink z slab if ws is small
    while (slabD > 1 && fixedf + (size_t)1024 * slabD * 960 > wsf) slabD >>= 1;

    build_B<<<6, 256, 0, stream>>>(B);
    build_W<<<720, 256, 0, stream>>>(W,
        (const float*)d_in[1], (const float*)d_in[2], (const float*)d_in[3],
        (const float*)d_in[4], (const float*)d_in[5],
        (const float*)d_in[6], (const float*)d_in[7], (const float*)d_in[8],
        (const float*)d_in[9], (const float*)d_in[10]);

    for (int d0 = 0; d0 < 32; d0 += slabD) {
        basis_conv<<<slabD * 320, 256, 0, stream>>>(x, z, B, d0);
        gemm_gate<<<slabD * 8, 256, 0, stream>>>(z, W, x1, d0);
    }
    for (int d0 = 0; d0 < 32; d0 += slabD) {
        basis_conv<<<slabD * 320, 256, 0, stream>>>(x1, z, B, d0);
        gemm_gate<<<slabD * 8, 256, 0, stream>>>(z, W + 92160, x2, d0);
    }
    final_k<<<2048, 256, 0, stream>>>(x2, wls, wlv, wpos, out);
}

// Round 4
// 600.343 us; speedup vs baseline: 1.3046x; 1.0182x over previous
//
#include <hip/hip_runtime.h>
#include <math.h>

// x: [1,32,32,32,80] fp32 (80 = 32 scalars + 16 vec*3)
// conv: low-rank kernel basis 12 = 3 radial * {1, Yd, Yh, Yw}
//   stage A (NEW, tap-pair): z[v][j*80+ci] fp32
//   stage B (R2 proven): y = z @ W fp32 VALU, gate -> x1 fp32 [v][80]
// out: [1,64,64,64,80] fp32

__device__ __forceinline__ int eps3(int a, int m, int b) {
    if (a == b || a == m || m == b) return 0;
    return ((a==0&&m==1&&b==2)||(a==1&&m==2&&b==0)||(a==2&&m==0&&b==1)) ? 1 : -1;
}

// ---------------------------------------------------------------- tap-pair table
// 40 pair records + 1 center record, 16 floats each:
//  [0]=off(+t) [1]=off(-t) (LDS float4-index into 6x6x20 halo tile, as int bits)
//  [4..6] = R_r(|t|)   [7+3r+m] = R_r * sqrt(3) * t_m / |t|
__global__ void build_tap(float* __restrict__ tap) {
    int t = threadIdx.x;
    if (t >= 125) return;
    int td = t / 25 - 2, th = (t / 5) % 5 - 2, tw = t % 5 - 2;
    int n2 = td*td + th*th + tw*tw;
    if (t == 62) {                       // center tap
        float* rec = tap + 40 * 16;
        rec[0] = __int_as_float(0); rec[1] = __int_as_float(0);
        for (int r = 0; r < 3; r++) {
            float tt = (0.f - 1.25f * (float)r) * 0.8f;
            rec[4 + r] = expf(-tt * tt);
        }
        return;
    }
    bool active = n2 <= 6;
    bool pos = (td > 0) || (td == 0 && th > 0) || (td == 0 && th == 0 && tw > 0);
    if (!(active && pos)) return;
    int idx = 0;                          // compact index among positive reps
    for (int q = 0; q < t; q++) {
        int qd = q / 25 - 2, qh = (q / 5) % 5 - 2, qw = q % 5 - 2;
        int m2 = qd*qd + qh*qh + qw*qw;
        bool p = (qd > 0) || (qd == 0 && qh > 0) || (qd == 0 && qh == 0 && qw > 0);
        if (m2 <= 6 && p) idx++;
    }
    float* rec = tap + idx * 16;
    rec[0] = __int_as_float((td+2)*120 + (th+2)*20 + (tw+2) - (2*120 + 2*20 + 2));
    rec[1] = __int_as_float((2-td)*120 + (2-th)*20 + (2-tw) - (2*120 + 2*20 + 2));
    float norm = sqrtf((float)n2);
    float comp[3] = {(float)td, (float)th, (float)tw};
    for (int r = 0; r < 3; r++) {
        float tt = (norm - 1.25f * (float)r) * 0.8f;
        float R = expf(-tt * tt);
        rec[4 + r] = R;
        for (int m = 0; m < 3; m++)
            rec[7 + r*3 + m] = R * 1.7320508075688772f * comp[m] / norm;
    }
}

// ---------------------------------------------------------------- W matrices (R2 verbatim)
// W[conv][j*80+ci][co], j = r*4+alpha.  2*12*80*96 = 184320 entries.
__global__ void build_W(float* __restrict__ W,
    const float* __restrict__ ss1, const float* __restrict__ sv1,
    const float* __restrict__ vs1, const float* __restrict__ vv01, const float* __restrict__ vv11,
    const float* __restrict__ ss2, const float* __restrict__ sv2,
    const float* __restrict__ vs2, const float* __restrict__ vv02, const float* __restrict__ vv12)
{
    int idx = threadIdx.x + blockIdx.x * 256;
    if (idx >= 184320) return;
    int conv = idx / 92160;
    int rem  = idx % 92160;
    int j  = rem / 7680;
    int ci = (rem / 96) % 80;
    int co = rem % 96;
    int r = j >> 2, al = j & 3;
    const float* ss  = conv ? ss2  : ss1;
    const float* sv  = conv ? sv2  : sv1;
    const float* vs  = conv ? vs2  : vs1;
    const float* vv0 = conv ? vv02 : vv01;
    const float* vv1 = conv ? vv12 : vv11;
    float val = 0.f;
    if (ci < 32) {
        if (co < 48) { if (al == 0) val = ss[(r*32 + ci)*48 + co]; }
        else {
            int o = (co - 48) / 3, m = (co - 48) % 3;
            if (al == m + 1) val = sv[(r*32 + ci)*16 + o];
        }
    } else {
        int i = (ci - 32) / 3, a = (ci - 32) % 3;
        if (co < 48) { if (al == a + 1) val = vs[(r*16 + i)*48 + co] * 0.5773502691896258f; }
        else {
            int o = (co - 48) / 3, b = (co - 48) % 3;
            if (al == 0) { if (a == b) val = vv0[(r*16 + i)*16 + o]; }
            else {
                int e = eps3(a, al - 1, b);
                if (e) val = vv1[(r*16 + i)*16 + o] * (float)e * 0.7071067811865476f;
            }
        }
    }
    W[idx] = val;
}

// ---------------------------------------------------------------- Stage A (tap-pair, fp32 out)
// Block: 2x2x16 voxel tile (64 v) x 4 ci-groups; LDS halo 6x6x20 per group.
// Tap-pair trick: acc_R += R*(x+ + x-), acc_Y += R*Y*(x+ - x-).
__global__ __launch_bounds__(256) void basis_conv3(
    const float* __restrict__ xin, float* __restrict__ z,
    const float* __restrict__ tap, int d0)
{
    __shared__ float xs[4][2880];        // 4 ci-groups x (720 float4) = 46 KB
    int tid = threadIdx.x;
    int cl = tid >> 6;                   // ci-group lane (wave-uniform)
    int vl64 = tid & 63;
    int dl = vl64 >> 5, hl = (vl64 >> 4) & 1, wl = vl64 & 15;
    int bid = blockIdx.x;
    int dt = d0 + ((bid >> 5) << 1);
    int h0 = ((bid >> 1) & 15) << 1;
    int w0 = (bid & 1) << 4;
    int vl = ((dt + dl - d0) << 10) + ((h0 + hl) << 5) + w0 + wl;  // slab-local
    float* zp = z + (size_t)vl * 960;

    for (int cb = 0; cb < 20; cb += 4) {
        __syncthreads();
        for (int i = tid; i < 2880; i += 256) {
            int sl = i / 720, rr = i - sl * 720;
            int dd = rr / 120, rm = rr - dd * 120;
            int hh = rm / 20, ww = rm - hh * 20;
            int gd = dt + dd - 2, gh = h0 + hh - 2, gw = w0 + ww - 2;
            float4 val = make_float4(0.f, 0.f, 0.f, 0.f);
            if (gd >= 0 && gd < 32 && gh >= 0 && gh < 32 && gw >= 0 && gw < 32)
                val = *reinterpret_cast<const float4*>(
                    xin + (size_t)(((gd << 5) + gh) * 32 + gw) * 80 + (cb + sl) * 4);
            *reinterpret_cast<float4*>(&xs[sl][rr * 4]) = val;
        }
        __syncthreads();
        const float* xp = &xs[cl][((dl + 2) * 120 + (hl + 2) * 20 + (wl + 2)) * 4];
        float acc[12][4];
        #pragma unroll
        for (int j = 0; j < 12; j++)
            #pragma unroll
            for (int c = 0; c < 4; c++) acc[j][c] = 0.f;
        {   // center
            const float* rec = tap + 640;
            float4 xc = *reinterpret_cast<const float4*>(xp);
            #pragma unroll
            for (int r = 0; r < 3; r++) {
                float R = rec[4 + r];
                acc[r*4][0] += R * xc.x; acc[r*4][1] += R * xc.y;
                acc[r*4][2] += R * xc.z; acc[r*4][3] += R * xc.w;
            }
        }
        for (int p = 0; p < 40; p++) {
            const float* rec = tap + p * 16;
            int op = __float_as_int(rec[0]) * 4, om = __float_as_int(rec[1]) * 4;
            float4 xa = *reinterpret_cast<const float4*>(xp + op);
            float4 xb = *reinterpret_cast<const float4*>(xp + om);
            float s[4], d[4];
            s[0] = xa.x + xb.x; s[1] = xa.y + xb.y; s[2] = xa.z + xb.z; s[3] = xa.w + xb.w;
            d[0] = xa.x - xb.x; d[1] = xa.y - xb.y; d[2] = xa.z - xb.z; d[3] = xa.w - xb.w;
            #pragma unroll
            for (int r = 0; r < 3; r++) {
                float R = rec[4 + r];
                #pragma unroll
                for (int c = 0; c < 4; c++) acc[r*4][c] += R * s[c];
                #pragma unroll
                for (int m = 0; m < 3; m++) {
                    float RY = rec[7 + r*3 + m];
                    #pragma unroll
                    for (int c = 0; c < 4; c++) acc[r*4 + m + 1][c] += RY * d[c];
                }
            }
        }
        int cig = cb + cl;
        #pragma unroll
        for (int j = 0; j < 12; j++)
            *reinterpret_cast<float4*>(zp + j * 80 + cig * 4) =
                make_float4(acc[j][0], acc[j][1], acc[j][2], acc[j][3]);
    }
}

// ---------------------------------------------------------------- Stage B (R2 verbatim)
__global__ __launch_bounds__(256) void gemm_gate(
    const float* __restrict__ z, const float* __restrict__ W,
    float* __restrict__ xout, int d0)
{
    __shared__ float smem[128 * 65 + 64 * 96];
    float* zt = smem;               // [128][65]  (+1 pad: odd stride, conflict-free)
    float* wt = smem + 128 * 65;    // [64][96]
    int t = threadIdx.x;
    int vg = t >> 4, cg = t & 15;
    int v0 = vg * 8, co0 = cg * 6;
    int vbase = blockIdx.x * 128;   // slab-local
    float acc[8][6];
    #pragma unroll
    for (int i = 0; i < 8; i++)
        #pragma unroll
        for (int j = 0; j < 6; j++) acc[i][j] = 0.f;

    for (int kc = 0; kc < 15; kc++) {
        #pragma unroll
        for (int l = 0; l < 8; l++) {            // z tile 128x64
            int idx = t + l * 256;
            int row = idx >> 4, c4 = idx & 15;
            float4 zv4 = *reinterpret_cast<const float4*>(
                z + (size_t)(vbase + row) * 960 + kc * 64 + c4 * 4);
            float* dst = zt + row * 65 + c4 * 4;
            dst[0] = zv4.x; dst[1] = zv4.y; dst[2] = zv4.z; dst[3] = zv4.w;
        }
        #pragma unroll
        for (int l = 0; l < 6; l++) {            // W tile 64x96
            int idx = t + l * 256;
            int row = idx / 24, c4 = idx % 24;
            *reinterpret_cast<float4*>(wt + row * 96 + c4 * 4) =
                *reinterpret_cast<const float4*>(W + (size_t)(kc * 64 + row) * 96 + c4 * 4);
        }
        __syncthreads();
        #pragma unroll 2
        for (int kk = 0; kk < 64; kk++) {
            float zv[8], wv[6];
            #pragma unroll
            for (int i = 0; i < 8; i++) zv[i] = zt[(v0 + i) * 65 + kk];
            #pragma unroll
            for (int j = 0; j < 6; j++) wv[j] = wt[kk * 96 + co0 + j];
            #pragma unroll
            for (int i = 0; i < 8; i++)
                #pragma unroll
                for (int j = 0; j < 6; j++) acc[i][j] += zv[i] * wv[j];
        }
        __syncthreads();
    }
    float* y = smem;                 // [128][96]
    #pragma unroll
    for (int i = 0; i < 8; i++)
        #pragma unroll
        for (int j = 0; j < 6; j++) y[(v0 + i) * 96 + co0 + j] = acc[i][j];
    __syncthreads();
    int gbase = d0 * 1024 + vbase;
    for (int idx = t; idx < 128 * 80; idx += 256) {
        int vr = idx / 80, c = idx % 80;
        const float* yr = y + vr * 96;
        float val;
        if (c < 32) val = fmaxf(yr[c], 0.f);
        else {
            int q = c - 32;
            float g = 1.f / (1.f + __expf(-yr[32 + q / 3]));
            val = yr[48 + q] * g;
        }
        xout[(size_t)(gbase + vr) * 80 + c] = val;
    }
}

// ---------------------------------------------------------------- Final head (R2 verbatim)
__global__ __launch_bounds__(256) void final_k(
    const float* __restrict__ x2, const float* __restrict__ wls,
    const float* __restrict__ wlv, const float* __restrict__ wpos,
    float* __restrict__ out)
{
    __shared__ float xv[16 * 81];
    __shared__ float coeff[16 * 161];
    __shared__ float s_wls[512];
    __shared__ float s_wlv[768];
    int t = threadIdx.x;
    int bid = blockIdx.x;
    int cw0 = (bid & 1) * 16;
    int ch  = (bid >> 1) & 31;
    int cd  = bid >> 6;
    float wp = wpos[0];
    {
        int base = ((cd * 32 + ch) * 32 + cw0) * 80;
        #pragma unroll
        for (int i = t; i < 1280; i += 256) {
            int vi = i / 80, c = i % 80;
            xv[vi * 81 + c] = x2[base + i];
        }
        for (int i = t; i < 512; i += 256) s_wls[i] = wls[i];
        for (int i = t; i < 768; i += 256) s_wlv[i] = wlv[i];
    }
    __syncthreads();
    {
        int vi = t >> 4, j = t & 15;
        const float* xp = xv + vi * 81;
        float* cf = coeff + vi * 161;
        #pragma unroll
        for (int l = 0; l < 10; l++) {
            int q = l * 16 + j;
            float sum = 0.f;
            if (q < 96) {
                int o = q / 3, m = q % 3;
                #pragma unroll
                for (int c = 0; c < 16; c++) sum += xp[32 + c * 3 + m] * s_wls[c * 32 + o];
            } else if (q < 112) {
                int o = q - 96;
                #pragma unroll
                for (int c = 0; c < 32; c++) sum += xp[c] * s_wlv[c * 16 + o];
            } else {
                int q2 = q - 112; int o = q2 / 3, m = q2 % 3;
                #pragma unroll
                for (int c = 0; c < 16; c++) sum += xp[32 + c * 3 + m] * s_wlv[(32 + c) * 16 + o];
            }
            cf[q] = sum;
        }
    }
    __syncthreads();
    const float scale = 0.14433756729740643f;
    #pragma unroll
    for (int f01 = 0; f01 < 4; f01++) {
        int fd = 2 * cd + (f01 >> 1), fh = 2 * ch + (f01 & 1);
        float p0 = wp * (float)(cd + (f01 >> 1) - 16);
        float p1 = wp * (float)(ch + (f01 & 1) - 16);
        size_t obase = (size_t)((fd * 64 + fh) * 64 + cw0 * 2) * 80;
        #pragma unroll
        for (int it = 0; it < 10; it++) {
            int idx = it * 256 + t;
            int fwl = idx / 80, c = idx - fwl * 80;
            int vi = fwl >> 1;
            float p2 = wp * (float)(cw0 + vi + (fwl & 1) - 16);
            const float* cf = coeff + vi * 161;
            float val;
            if (c < 32) {
                val = cf[c * 3] * p0 + cf[c * 3 + 1] * p1 + cf[c * 3 + 2] * p2;
            } else {
                int q = c - 32, o = q / 3, m = q - o * 3;
                float A = cf[96 + o];
                const float* w2 = cf + 112 + o * 3;
                float pm, crm;
                if (m == 0)      { pm = p0; crm = w2[1] * p2 - w2[2] * p1; }
                else if (m == 1) { pm = p1; crm = w2[2] * p0 - w2[0] * p2; }
                else             { pm = p2; crm = w2[0] * p1 - w2[1] * p0; }
                val = A * pm + crm * 0.7071067811865476f;
            }
            out[obase + idx] = val * scale;
        }
    }
}

// ----------------------------------------------------------------
extern "C" void kernel_launch(void* const* d_in, const int* in_sizes, int n_in,
                              void* d_out, int out_size, void* d_ws, size_t ws_size,
                              hipStream_t stream)
{
    const float* x    = (const float*)d_in[0];
    const float* wpos = (const float*)d_in[11];
    const float* wls  = (const float*)d_in[12];
    const float* wlv  = (const float*)d_in[13];
    float* out = (float*)d_out;
    float* ws  = (float*)d_ws;

    float* tap = ws;                        // 656 floats -> pad 1024
    float* W   = ws + 1024;                 // 184320
    float* x1  = ws + 1024 + 184320;        // 2621440
    float* x2  = x1 + 2621440;
    float* z   = x2 + 2621440;
    size_t fixedf = 1024 + 184320 + 2ull * 2621440;
    size_t wsf = ws_size / 4;
    int slabD = 32;                          // shrink z slab if ws is small
    while (slabD > 2 && fixedf + (size_t)1024 * slabD * 960 > wsf) slabD >>= 1;

    build_tap<<<1, 128, 0, stream>>>(tap);
    build_W<<<720, 256, 0, stream>>>(W,
        (const float*)d_in[1], (const float*)d_in[2], (const float*)d_in[3],
        (const float*)d_in[4], (const float*)d_in[5],
        (const float*)d_in[6], (const float*)d_in[7], (const float*)d_in[8],
        (const float*)d_in[9], (const float*)d_in[10]);

    for (int d0 = 0; d0 < 32; d0 += slabD) {
        basis_conv3<<<slabD * 16, 256, 0, stream>>>(x, z, tap, d0);
        gemm_gate<<<slabD * 8, 256, 0, stream>>>(z, W, x1, d0);
    }
    for (int d0 = 0; d0 < 32; d0 += slabD) {
        basis_conv3<<<slabD * 16, 256, 0, stream>>>(x1, z, tap, d0);
        gemm_gate<<<slabD * 8, 256, 0, stream>>>(z, W + 92160, x2, d0);
    }
    final_k<<<2048, 256, 0, stream>>>(x2, wls, wlv, wpos, out);
}